// Round 2
// baseline (284.028 us; speedup 1.0000x reference)
//
#include <hip/hip_runtime.h>

#define BB 512
#define DD 128
#define HD 64

typedef float v2f __attribute__((ext_vector_type(2)));
#define FMA2(a, b, c) __builtin_elementwise_fma((v2f)(a), (v2f)(b), (v2f)(c))

// ---- workspace layout (float offsets) ----
#define OFF_E1 0                     // 3 * 512 * 128  (normalized emb1, packed (d, d+64))
#define OFF_E2 (3*BB*DD)             // 3 * 512 * 128
#define OFF_C1 (2*3*BB*DD)           // 2 * 512 * 128  (cert1 layers 1,2 packed)
#define OFF_C2 (OFF_C1 + 2*BB*DD)    // 2 * 512 * 128
#define OFF_AB (OFF_C2 + 2*BB*DD)    // 2 layers * (A[128], B[128]); A=-log2e*alpha, B=-log2e*beta
#define OFF_LNK (OFF_AB + 512)       // 2 links * (idx[3][128] interleaved, w[3][128]) = 2*768
// R13: precomputed layer-1 gather factors (link-0 only, row-dependent):
#define OFF_UG (OFF_LNK + 1536)      // 512*3*128: i-side -2*w1k*u0[idx1k], packed (e,e+64)
#define OFF_SU (OFF_UG + 3*BB*DD)    // 512*128:   sum_k w1k*u0[idx1k]^2
#define OFF_VG (OFF_SU + BB*DD)      // 512*3*128: j-side v0[idx1k]
#define OFF_SV (OFF_VG + 3*BB*DD)    // 512*128
#define WS_FLOATS (OFF_SV + BB*DD)   // ~4.5 MB

__device__ __forceinline__ float wave_sum64(float v) {
  #pragma unroll
  for (int off = 1; off < 64; off <<= 1) v += __shfl_xor(v, off, 64);
  return v;
}

// DPP lane-shift add: pure VALU pipe. Sum of all 64 lanes lands in lane 63.
template <int CTRL>
__device__ __forceinline__ float dpp_mov(float x) {
  int i = __builtin_bit_cast(int, x);
  int r = __builtin_amdgcn_update_dpp(0, i, CTRL, 0xF, 0xF, false);
  return __builtin_bit_cast(float, r);
}
__device__ __forceinline__ float dpp_wave_sum_lane63(float v) {
  v += dpp_mov<0x111>(v);  // row_shr:1
  v += dpp_mov<0x112>(v);  // row_shr:2
  v += dpp_mov<0x114>(v);  // row_shr:4
  v += dpp_mov<0x118>(v);  // row_shr:8
  v += dpp_mov<0x142>(v);  // row_bcast:15
  v += dpp_mov<0x143>(v);  // row_bcast:31
  return v;
}

// ---- prep 1 (unchanged): links first, then normalize/pack ----
struct PackArgs { const float* src[10]; };

__global__ __launch_bounds__(256) void prep_kernel(PackArgs a,
                                                   const float* __restrict__ lnk0,
                                                   const float* __restrict__ lnk1,
                                                   const float* __restrict__ a1,
                                                   const float* __restrict__ b1,
                                                   const float* __restrict__ a2,
                                                   const float* __restrict__ b2,
                                                   float* __restrict__ ws) {
  const int tid  = threadIdx.x;
  const int lane = tid & 63;
  if (blockIdx.x >= 64) {
    const int gw   = (blockIdx.x - 64) * 4 + (tid >> 6);
    const int arr  = gw >> 9;                       // 0..9
    const int row  = gw & 511;
    const float* s = a.src[arr];
    float lo = s[row * DD + lane];
    float hi = s[row * DD + lane + 64];
    float scale = 1.0f;
    if (arr < 6) {  // embeddings: L2 normalize
      float ss = wave_sum64(lo * lo + hi * hi);
      scale = 1.0f / fmaxf(sqrtf(ss), 1e-12f);
    }
    float* dst;
    if (arr < 3)      dst = ws + OFF_E1 + arr * (BB * DD);
    else if (arr < 6) dst = ws + OFF_E2 + (arr - 3) * (BB * DD);
    else if (arr < 8) dst = ws + OFF_C1 + (arr - 6) * (BB * DD);
    else              dst = ws + OFF_C2 + (arr - 8) * (BB * DD);
    ((float2*)dst)[row * HD + lane] = make_float2(lo * scale, hi * scale);
  } else {
    // one wave per (l, e) column; lane d holds L[d][e] and L[d+64][e]
    const int task = blockIdx.x * 4 + (tid >> 6);   // 0..255
    const int l = task >> 7, e = task & 127;
    const float* L = l ? lnk1 : lnk0;
    float v0 = L[lane * DD + e];
    float v1 = L[(lane + 64) * DD + e];
    float bv[3]; int bd[3];
    #pragma unroll
    for (int k = 0; k < 3; ++k) {
      float lv; int ld;
      if (v0 >= v1) { lv = v0; ld = lane; } else { lv = v1; ld = lane + 64; }
      #pragma unroll
      for (int off = 1; off < 64; off <<= 1) {
        float ov = __shfl_xor(lv, off, 64);
        int   od = __shfl_xor(ld, off, 64);
        if (ov > lv || (ov == lv && od < ld)) { lv = ov; ld = od; }
      }
      bv[k] = lv; bd[k] = ld;             // same in all lanes
      if (ld == lane)      v0 = -1e30f;   // remove winner
      if (ld == lane + 64) v1 = -1e30f;
    }
    if (lane == 0) {
      float inv = 1.0f / (bv[0] + bv[1] + bv[2] + 1e-8f);
      int*   li = (int*)(ws + OFF_LNK + l * 768);
      float* lw =        ws + OFF_LNK + l * 768 + 384;
      // indices pre-transformed for interleaved LDS h-layout:
      // dim d lives at LDS word ((d&63)<<1) | (d>>6)
      li[e]       = ((bd[0] & 63) << 1) | (bd[0] >> 6);
      li[128 + e] = ((bd[1] & 63) << 1) | (bd[1] >> 6);
      li[256 + e] = ((bd[2] & 63) << 1) | (bd[2] >> 6);
      lw[e] = bv[0] * inv; lw[128 + e] = bv[1] * inv; lw[256 + e] = bv[2] * inv;
      const float NL2E = -1.4426950408889634f;
      const float* al = l ? a2 : a1;
      const float* bl = l ? b2 : b1;
      ws[OFF_AB + l * 256 + e]       = NL2E * al[e];
      ws[OFF_AB + l * 256 + 128 + e] = NL2E * bl[e];
    }
  }
}

// ---- prep 2 (R13, verified bit-exact): hoist ALL layer-1 (link-0) gathers.
// 1024 waves; FMA2 sequences bit-identical to the old in-main U/SU and V/SV.
__global__ __launch_bounds__(256) void prep2_kernel(float* __restrict__ ws) {
  __shared__ float pl[4][DD];
  const int tid  = threadIdx.x;
  const int lane = tid & 63;
  const int w    = tid >> 6;
  float*  p  = pl[w];
  float2* p2 = (float2*)p;
  const int gw   = blockIdx.x * 4 + w;   // 0..1023
  const int side = gw >> 9;              // 0: emb1 (U-side), 1: emb2 (V-side)
  const int row  = gw & 511;
  const int*   li0 = (const int*)(ws + OFF_LNK);
  const float* lw0 = ws + OFF_LNK + 384;
  int I[3][2]; v2f W[3];
  #pragma unroll
  for (int k = 0; k < 3; ++k) {
    I[k][0] = li0[k * 128 + lane]; I[k][1] = li0[k * 128 + lane + 64];
    W[k].x  = lw0[k * 128 + lane]; W[k].y  = lw0[k * 128 + lane + 64];
  }
  const float2* Ep = (const float2*)(ws + (side ? OFF_E2 : OFF_E1));
  float2 u0 = Ep[row * HD + lane];       // normalized layer-0 row (from prep1)
  p2[lane] = u0;                         // same-wave DS: in-order, no barrier
  v2f S = (v2f)0.0f; v2f G[3];
  #pragma unroll
  for (int k = 0; k < 3; ++k) {
    v2f a; a.x = p[I[k][0]]; a.y = p[I[k][1]];
    v2f t = W[k] * a;
    S = FMA2(t, a, S);                   // sum_k w_k * x[d_k]^2 (matches old SU/SV)
    G[k] = side ? a : (-2.0f * t);       // V-side: raw gather; U-side: -2*w_k*u0[d_k]
  }
  float2* Gp = (float2*)(ws + (side ? OFF_VG : OFF_UG));
  float2* Sp = (float2*)(ws + (side ? OFF_SV : OFF_SU));
  #pragma unroll
  for (int k = 0; k < 3; ++k) Gp[(row * 3 + k) * HD + lane] = make_float2(G[k].x, G[k].y);
  Sp[row * HD + lane] = make_float2(S.x, S.y);
}

// ---- main (R14): R12's fused PHASE+CONSUME single-plane body (no q-pipeline,
// no unroll-2 — R13 post-mortem: those spilled ~9 MB of scratch at the forced
// 64-VGPR budget and regressed 47->57 us). Layer-1 gathers come from the
// prep2 tables (L2-resident). The real lever this round is TLP: VGPR=64 and
// LDS=2KB permit 8 blocks/CU but the old grid (1024) delivered only 4.
// j-chunk 16 -> 8, grid 1024 -> 2048 blocks = 32 waves/CU to hide the
// L2-reload + LDS-round-trip chains the compiler leaves in the loop.
__global__ __launch_bounds__(256, 8) void main_kernel(const float* __restrict__ ws,
                                                      float* __restrict__ out) {
  __shared__ float hbuf[4][DD];
  const int tid  = threadIdx.x;
  const int lane = tid & 63;
  const int w    = tid >> 6;
  float*  hb  = hbuf[w];
  float2* hb2 = (float2*)hb;             // hb2[l] = (dim l, dim l+64)  [R6/R8-verified]
  const int gw = blockIdx.x * 4 + w;     // 8192 waves
  const int i0 = (gw >> 6) * 4;          // 128 i-tiles of 4
  const int j0 = (gw & 63) * 8;          // 64 j-chunks of 8

  const int*   li1 = (const int*)(ws + OFF_LNK + 768);
  const float* lw1 = ws + OFF_LNK + 768 + 384;
  int I2[3][2]; v2f W2[3];
  #pragma unroll
  for (int k = 0; k < 3; ++k) {
    I2[k][0] = li1[k * 128 + lane]; I2[k][1] = li1[k * 128 + lane + 64];
    W2[k].x  = lw1[k * 128 + lane]; W2[k].y  = lw1[k * 128 + lane + 64];
  }
  v2f Av1, Bv1, Av2, Bv2;
  Av1.x = ws[OFF_AB + lane];       Av1.y = ws[OFF_AB + lane + 64];
  Bv1.x = ws[OFF_AB + 128 + lane]; Bv1.y = ws[OFF_AB + 128 + lane + 64];
  Av2.x = ws[OFF_AB + 256 + lane]; Av2.y = ws[OFF_AB + 256 + lane + 64];
  Bv2.x = ws[OFF_AB + 384 + lane]; Bv2.y = ws[OFF_AB + 384 + lane + 64];

  const float2* E1p = (const float2*)(ws + OFF_E1);
  const float2* E2p = (const float2*)(ws + OFF_E2);
  const float2* C1p = (const float2*)(ws + OFF_C1);
  const float2* C2p = (const float2*)(ws + OFF_C2);
  const float2* UGp = (const float2*)(ws + OFF_UG);
  const float2* SUp = (const float2*)(ws + OFF_SU);
  const float2* VGp = (const float2*)(ws + OFF_VG);
  const float2* SVp = (const float2*)(ws + OFF_SV);
  #define LD2(p, idx) ({ float2 _t = (p)[idx]; v2f _v; _v.x = _t.x; _v.y = _t.y; _v; })

  // i-tile state (amortized over 8 j's; compiler may re-load from L2 — that's
  // fine, the point of this round is enough waves to hide those reloads)
  v2f ug[4][3], su[4], u1[4], u2[4], c11[4], c12[4];
  #pragma unroll
  for (int ii = 0; ii < 4; ++ii) {
    const int i = i0 + ii;
    #pragma unroll
    for (int k = 0; k < 3; ++k) ug[ii][k] = LD2(UGp, (i * 3 + k) * HD + lane);
    su[ii]  = LD2(SUp, i * HD + lane);
    u1[ii]  = LD2(E1p, (1 * BB + i) * HD + lane);
    u2[ii]  = LD2(E1p, (2 * BB + i) * HD + lane);
    c11[ii] = LD2(C1p, (0 * BB + i) * HD + lane);
    c12[ii] = LD2(C1p, (1 * BB + i) * HD + lane);
  }

  #pragma unroll 1
  for (int jj = 0; jj < 8; ++jj) {
    const int j = j0 + jj;
    v2f vg0  = LD2(VGp, (j * 3 + 0) * HD + lane);
    v2f vg1  = LD2(VGp, (j * 3 + 1) * HD + lane);
    v2f vg2v = LD2(VGp, (j * 3 + 2) * HD + lane);
    v2f sv   = LD2(SVp, j * HD + lane);
    const v2f v1  = LD2(E2p, (1 * BB + j) * HD + lane);
    const v2f v2  = LD2(E2p, (2 * BB + j) * HD + lane);
    const v2f g21 = LD2(C2p, (0 * BB + j) * HD + lane);
    const v2f g22 = LD2(C2p, (1 * BB + j) * HD + lane);
    #pragma unroll
    for (int ii = 0; ii < 4; ++ii) {
      // layer 1: g from precomputed factored gathers (registers only, pk-fma)
      v2f g1 = FMA2(ug[ii][0], vg0, FMA2(ug[ii][1], vg1,
                FMA2(ug[ii][2], vg2v, su[ii] + sv)));
      v2f d1 = u1[ii] - v1;
      v2f n1 = d1 * d1;
      v2f x1 = FMA2(c11[ii] * g21, Av1, Bv1);
      v2f t1, P1;
      t1.x = __builtin_amdgcn_exp2f(x1.x); t1.y = __builtin_amdgcn_exp2f(x1.y);
      P1.x = __builtin_amdgcn_rcpf(1.0f + t1.x); P1.y = __builtin_amdgcn_rcpf(1.0f + t1.y);
      v2f h1 = FMA2(P1, n1 - g1, g1);           // (1-P)*g + P*n
      // layer 2: per-pair LDS gather (R6/R8-verified float2-store/float-load)
      hb2[lane] = make_float2(h1.x, h1.y);
      v2f g2;
      g2.x = hb[I2[0][0]] * W2[0].x + hb[I2[1][0]] * W2[1].x + hb[I2[2][0]] * W2[2].x;
      g2.y = hb[I2[0][1]] * W2[0].y + hb[I2[1][1]] * W2[1].y + hb[I2[2][1]] * W2[2].y;
      v2f d2 = u2[ii] - v2;
      v2f n2 = d2 * d2;
      v2f x2 = FMA2(c12[ii] * g22, Av2, Bv2);
      v2f t2, P2;
      t2.x = __builtin_amdgcn_exp2f(x2.x); t2.y = __builtin_amdgcn_exp2f(x2.y);
      P2.x = __builtin_amdgcn_rcpf(1.0f + t2.x); P2.y = __builtin_amdgcn_rcpf(1.0f + t2.y);
      v2f h2 = FMA2(P2, n2 - g2, g2);
      // reduce over 128 dims: DPP (VALU pipe), sum lands in lane 63
      float s = dpp_wave_sum_lane63(h2.x + h2.y);
      if (lane == 63) out[(i0 + ii) * BB + j] = s;
    }
  }
}

extern "C" void kernel_launch(void* const* d_in, const int* in_sizes, int n_in,
                              void* d_out, int out_size, void* d_ws, size_t ws_size,
                              hipStream_t stream) {
  (void)in_sizes; (void)n_in; (void)out_size; (void)ws_size;
  // dict order: [0]emb1_0 [1]emb2_0 [2]cert1_0 [3]cert2_0 [4]alpha_0 [5]beta_0
  //             [6..11] layer1, [12..17] layer2, [18]link_0 [19]link_1
  float* ws = (float*)d_ws;
  PackArgs pa;
  pa.src[0] = (const float*)d_in[0];  pa.src[1] = (const float*)d_in[6];  pa.src[2] = (const float*)d_in[12];
  pa.src[3] = (const float*)d_in[1];  pa.src[4] = (const float*)d_in[7];  pa.src[5] = (const float*)d_in[13];
  pa.src[6] = (const float*)d_in[8];  pa.src[7] = (const float*)d_in[14];
  pa.src[8] = (const float*)d_in[9];  pa.src[9] = (const float*)d_in[15];
  hipLaunchKernelGGL(prep_kernel, dim3(1344), dim3(256), 0, stream, pa,
                     (const float*)d_in[18], (const float*)d_in[19],
                     (const float*)d_in[10], (const float*)d_in[11],
                     (const float*)d_in[16], (const float*)d_in[17], ws);
  hipLaunchKernelGGL(prep2_kernel, dim3(256), dim3(256), 0, stream, ws);
  hipLaunchKernelGGL(main_kernel, dim3(2048), dim3(256), 0, stream,
                     (const float*)ws, (float*)d_out);
}

// Round 3
// 137.633 us; speedup vs baseline: 2.0637x; 2.0637x over previous
//
#include <hip/hip_runtime.h>

#define BB 512
#define DD 128
#define HD 64

typedef float v2f __attribute__((ext_vector_type(2)));
#define FMA2(a, b, c) __builtin_elementwise_fma((v2f)(a), (v2f)(b), (v2f)(c))

// ---- workspace layout (float offsets) ----
#define OFF_E1 0                     // 3 * 512 * 128  (normalized emb1, packed (d, d+64))
#define OFF_E2 (3*BB*DD)             // 3 * 512 * 128
#define OFF_C1 (2*3*BB*DD)           // 2 * 512 * 128  (cert1 layers 1,2 packed)
#define OFF_C2 (OFF_C1 + 2*BB*DD)    // 2 * 512 * 128
#define OFF_AB (OFF_C2 + 2*BB*DD)    // 2 layers * (A[128], B[128]); A=-log2e*alpha, B=-log2e*beta
#define OFF_LNK (OFF_AB + 512)       // 2 links * (idx[3][128] interleaved, w[3][128]) = 2*768
// precomputed layer-1 gather factors (link-0 only, row-dependent):
#define OFF_UG (OFF_LNK + 1536)      // 512*3*128: i-side -2*w1k*u0[idx1k], packed (e,e+64)
#define OFF_SU (OFF_UG + 3*BB*DD)    // 512*128:   sum_k w1k*u0[idx1k]^2
#define OFF_VG (OFF_SU + BB*DD)      // 512*3*128: j-side v0[idx1k]
#define OFF_SV (OFF_VG + 3*BB*DD)    // 512*128
#define WS_FLOATS (OFF_SV + BB*DD)   // ~4.5 MB

__device__ __forceinline__ float wave_sum64(float v) {
  #pragma unroll
  for (int off = 1; off < 64; off <<= 1) v += __shfl_xor(v, off, 64);
  return v;
}

// DPP lane-shift add: pure VALU pipe. Sum of all 64 lanes lands in lane 63.
template <int CTRL>
__device__ __forceinline__ float dpp_mov(float x) {
  int i = __builtin_bit_cast(int, x);
  int r = __builtin_amdgcn_update_dpp(0, i, CTRL, 0xF, 0xF, false);
  return __builtin_bit_cast(float, r);
}
__device__ __forceinline__ float dpp_wave_sum_lane63(float v) {
  v += dpp_mov<0x111>(v);  // row_shr:1
  v += dpp_mov<0x112>(v);  // row_shr:2
  v += dpp_mov<0x114>(v);  // row_shr:4
  v += dpp_mov<0x118>(v);  // row_shr:8
  v += dpp_mov<0x142>(v);  // row_bcast:15
  v += dpp_mov<0x143>(v);  // row_bcast:31
  return v;
}

// ---- prep 1 (unchanged): links first, then normalize/pack ----
struct PackArgs { const float* src[10]; };

__global__ __launch_bounds__(256) void prep_kernel(PackArgs a,
                                                   const float* __restrict__ lnk0,
                                                   const float* __restrict__ lnk1,
                                                   const float* __restrict__ a1,
                                                   const float* __restrict__ b1,
                                                   const float* __restrict__ a2,
                                                   const float* __restrict__ b2,
                                                   float* __restrict__ ws) {
  const int tid  = threadIdx.x;
  const int lane = tid & 63;
  if (blockIdx.x >= 64) {
    const int gw   = (blockIdx.x - 64) * 4 + (tid >> 6);
    const int arr  = gw >> 9;                       // 0..9
    const int row  = gw & 511;
    const float* s = a.src[arr];
    float lo = s[row * DD + lane];
    float hi = s[row * DD + lane + 64];
    float scale = 1.0f;
    if (arr < 6) {  // embeddings: L2 normalize
      float ss = wave_sum64(lo * lo + hi * hi);
      scale = 1.0f / fmaxf(sqrtf(ss), 1e-12f);
    }
    float* dst;
    if (arr < 3)      dst = ws + OFF_E1 + arr * (BB * DD);
    else if (arr < 6) dst = ws + OFF_E2 + (arr - 3) * (BB * DD);
    else if (arr < 8) dst = ws + OFF_C1 + (arr - 6) * (BB * DD);
    else              dst = ws + OFF_C2 + (arr - 8) * (BB * DD);
    ((float2*)dst)[row * HD + lane] = make_float2(lo * scale, hi * scale);
  } else {
    // one wave per (l, e) column; lane d holds L[d][e] and L[d+64][e]
    const int task = blockIdx.x * 4 + (tid >> 6);   // 0..255
    const int l = task >> 7, e = task & 127;
    const float* L = l ? lnk1 : lnk0;
    float v0 = L[lane * DD + e];
    float v1 = L[(lane + 64) * DD + e];
    float bv[3]; int bd[3];
    #pragma unroll
    for (int k = 0; k < 3; ++k) {
      float lv; int ld;
      if (v0 >= v1) { lv = v0; ld = lane; } else { lv = v1; ld = lane + 64; }
      #pragma unroll
      for (int off = 1; off < 64; off <<= 1) {
        float ov = __shfl_xor(lv, off, 64);
        int   od = __shfl_xor(ld, off, 64);
        if (ov > lv || (ov == lv && od < ld)) { lv = ov; ld = od; }
      }
      bv[k] = lv; bd[k] = ld;             // same in all lanes
      if (ld == lane)      v0 = -1e30f;   // remove winner
      if (ld == lane + 64) v1 = -1e30f;
    }
    if (lane == 0) {
      float inv = 1.0f / (bv[0] + bv[1] + bv[2] + 1e-8f);
      int*   li = (int*)(ws + OFF_LNK + l * 768);
      float* lw =        ws + OFF_LNK + l * 768 + 384;
      // indices pre-transformed for interleaved LDS h-layout:
      // dim d lives at LDS word ((d&63)<<1) | (d>>6)
      li[e]       = ((bd[0] & 63) << 1) | (bd[0] >> 6);
      li[128 + e] = ((bd[1] & 63) << 1) | (bd[1] >> 6);
      li[256 + e] = ((bd[2] & 63) << 1) | (bd[2] >> 6);
      lw[e] = bv[0] * inv; lw[128 + e] = bv[1] * inv; lw[256 + e] = bv[2] * inv;
      const float NL2E = -1.4426950408889634f;
      const float* al = l ? a2 : a1;
      const float* bl = l ? b2 : b1;
      ws[OFF_AB + l * 256 + e]       = NL2E * al[e];
      ws[OFF_AB + l * 256 + 128 + e] = NL2E * bl[e];
    }
  }
}

// ---- prep 2 (verified bit-exact): hoist ALL layer-1 (link-0) gathers.
// 1024 waves; FMA2 sequences bit-identical to the old in-main U/SU and V/SV.
__global__ __launch_bounds__(256) void prep2_kernel(float* __restrict__ ws) {
  __shared__ float pl[4][DD];
  const int tid  = threadIdx.x;
  const int lane = tid & 63;
  const int w    = tid >> 6;
  float*  p  = pl[w];
  float2* p2 = (float2*)p;
  const int gw   = blockIdx.x * 4 + w;   // 0..1023
  const int side = gw >> 9;              // 0: emb1 (U-side), 1: emb2 (V-side)
  const int row  = gw & 511;
  const int*   li0 = (const int*)(ws + OFF_LNK);
  const float* lw0 = ws + OFF_LNK + 384;
  int I[3][2]; v2f W[3];
  #pragma unroll
  for (int k = 0; k < 3; ++k) {
    I[k][0] = li0[k * 128 + lane]; I[k][1] = li0[k * 128 + lane + 64];
    W[k].x  = lw0[k * 128 + lane]; W[k].y  = lw0[k * 128 + lane + 64];
  }
  const float2* Ep = (const float2*)(ws + (side ? OFF_E2 : OFF_E1));
  float2 u0 = Ep[row * HD + lane];       // normalized layer-0 row (from prep1)
  p2[lane] = u0;                         // same-wave DS: in-order, no barrier
  v2f S = (v2f)0.0f; v2f G[3];
  #pragma unroll
  for (int k = 0; k < 3; ++k) {
    v2f a; a.x = p[I[k][0]]; a.y = p[I[k][1]];
    v2f t = W[k] * a;
    S = FMA2(t, a, S);                   // sum_k w_k * x[d_k]^2 (matches old SU/SV)
    G[k] = side ? a : (-2.0f * t);       // V-side: raw gather; U-side: -2*w_k*u0[d_k]
  }
  float2* Gp = (float2*)(ws + (side ? OFF_VG : OFF_UG));
  float2* Sp = (float2*)(ws + (side ? OFF_SV : OFF_SU));
  #pragma unroll
  for (int k = 0; k < 3; ++k) Gp[(row * 3 + k) * HD + lane] = make_float2(G[k].x, G[k].y);
  Sp[row * HD + lane] = make_float2(S.x, S.y);
}

// ---- main (R15): R14 body verbatim, launch bounds REVERTED to (256, 4).
// R14 post-mortem: __launch_bounds__(256,8) forced VGPR 64->32 and spilled
// the whole working set to scratch (FETCH 477 MB, WRITE 136 MB, 194 us).
// The 2nd launch_bounds arg is a register-allocator MINIMUM; (256,4) still
// lets the HW schedule 8 blocks/CU because actual VGPR use is 64
// (8 waves/SIMD x 64 = 512 = full file). Grid 2048 (j-chunk 8) is the TLP
// lever that R12 lacked (1024 blocks = only 4 blocks/CU, 32% occupancy).
__global__ __launch_bounds__(256, 4) void main_kernel(const float* __restrict__ ws,
                                                      float* __restrict__ out) {
  __shared__ float hbuf[4][DD];
  const int tid  = threadIdx.x;
  const int lane = tid & 63;
  const int w    = tid >> 6;
  float*  hb  = hbuf[w];
  float2* hb2 = (float2*)hb;             // hb2[l] = (dim l, dim l+64)  [R6/R8-verified]
  const int gw = blockIdx.x * 4 + w;     // 8192 waves
  const int i0 = (gw >> 6) * 4;          // 128 i-tiles of 4
  const int j0 = (gw & 63) * 8;          // 64 j-chunks of 8

  const int*   li1 = (const int*)(ws + OFF_LNK + 768);
  const float* lw1 = ws + OFF_LNK + 768 + 384;
  int I2[3][2]; v2f W2[3];
  #pragma unroll
  for (int k = 0; k < 3; ++k) {
    I2[k][0] = li1[k * 128 + lane]; I2[k][1] = li1[k * 128 + lane + 64];
    W2[k].x  = lw1[k * 128 + lane]; W2[k].y  = lw1[k * 128 + lane + 64];
  }
  v2f Av1, Bv1, Av2, Bv2;
  Av1.x = ws[OFF_AB + lane];       Av1.y = ws[OFF_AB + lane + 64];
  Bv1.x = ws[OFF_AB + 128 + lane]; Bv1.y = ws[OFF_AB + 128 + lane + 64];
  Av2.x = ws[OFF_AB + 256 + lane]; Av2.y = ws[OFF_AB + 256 + lane + 64];
  Bv2.x = ws[OFF_AB + 384 + lane]; Bv2.y = ws[OFF_AB + 384 + lane + 64];

  const float2* E1p = (const float2*)(ws + OFF_E1);
  const float2* E2p = (const float2*)(ws + OFF_E2);
  const float2* C1p = (const float2*)(ws + OFF_C1);
  const float2* C2p = (const float2*)(ws + OFF_C2);
  const float2* UGp = (const float2*)(ws + OFF_UG);
  const float2* SUp = (const float2*)(ws + OFF_SU);
  const float2* VGp = (const float2*)(ws + OFF_VG);
  const float2* SVp = (const float2*)(ws + OFF_SV);
  #define LD2(p, idx) ({ float2 _t = (p)[idx]; v2f _v; _v.x = _t.x; _v.y = _t.y; _v; })

  // i-tile state (amortized over 8 j's)
  v2f ug[4][3], su[4], u1[4], u2[4], c11[4], c12[4];
  #pragma unroll
  for (int ii = 0; ii < 4; ++ii) {
    const int i = i0 + ii;
    #pragma unroll
    for (int k = 0; k < 3; ++k) ug[ii][k] = LD2(UGp, (i * 3 + k) * HD + lane);
    su[ii]  = LD2(SUp, i * HD + lane);
    u1[ii]  = LD2(E1p, (1 * BB + i) * HD + lane);
    u2[ii]  = LD2(E1p, (2 * BB + i) * HD + lane);
    c11[ii] = LD2(C1p, (0 * BB + i) * HD + lane);
    c12[ii] = LD2(C1p, (1 * BB + i) * HD + lane);
  }

  #pragma unroll 1
  for (int jj = 0; jj < 8; ++jj) {
    const int j = j0 + jj;
    v2f vg0  = LD2(VGp, (j * 3 + 0) * HD + lane);
    v2f vg1  = LD2(VGp, (j * 3 + 1) * HD + lane);
    v2f vg2v = LD2(VGp, (j * 3 + 2) * HD + lane);
    v2f sv   = LD2(SVp, j * HD + lane);
    const v2f v1  = LD2(E2p, (1 * BB + j) * HD + lane);
    const v2f v2  = LD2(E2p, (2 * BB + j) * HD + lane);
    const v2f g21 = LD2(C2p, (0 * BB + j) * HD + lane);
    const v2f g22 = LD2(C2p, (1 * BB + j) * HD + lane);
    #pragma unroll
    for (int ii = 0; ii < 4; ++ii) {
      // layer 1: g from precomputed factored gathers (registers only, pk-fma)
      v2f g1 = FMA2(ug[ii][0], vg0, FMA2(ug[ii][1], vg1,
                FMA2(ug[ii][2], vg2v, su[ii] + sv)));
      v2f d1 = u1[ii] - v1;
      v2f n1 = d1 * d1;
      v2f x1 = FMA2(c11[ii] * g21, Av1, Bv1);
      v2f t1, P1;
      t1.x = __builtin_amdgcn_exp2f(x1.x); t1.y = __builtin_amdgcn_exp2f(x1.y);
      P1.x = __builtin_amdgcn_rcpf(1.0f + t1.x); P1.y = __builtin_amdgcn_rcpf(1.0f + t1.y);
      v2f h1 = FMA2(P1, n1 - g1, g1);           // (1-P)*g + P*n
      // layer 2: per-pair LDS gather (R6/R8-verified float2-store/float-load)
      hb2[lane] = make_float2(h1.x, h1.y);
      v2f g2;
      g2.x = hb[I2[0][0]] * W2[0].x + hb[I2[1][0]] * W2[1].x + hb[I2[2][0]] * W2[2].x;
      g2.y = hb[I2[0][1]] * W2[0].y + hb[I2[1][1]] * W2[1].y + hb[I2[2][1]] * W2[2].y;
      v2f d2 = u2[ii] - v2;
      v2f n2 = d2 * d2;
      v2f x2 = FMA2(c12[ii] * g22, Av2, Bv2);
      v2f t2, P2;
      t2.x = __builtin_amdgcn_exp2f(x2.x); t2.y = __builtin_amdgcn_exp2f(x2.y);
      P2.x = __builtin_amdgcn_rcpf(1.0f + t2.x); P2.y = __builtin_amdgcn_rcpf(1.0f + t2.y);
      v2f h2 = FMA2(P2, n2 - g2, g2);
      // reduce over 128 dims: DPP (VALU pipe), sum lands in lane 63
      float s = dpp_wave_sum_lane63(h2.x + h2.y);
      if (lane == 63) out[(i0 + ii) * BB + j] = s;
    }
  }
}

extern "C" void kernel_launch(void* const* d_in, const int* in_sizes, int n_in,
                              void* d_out, int out_size, void* d_ws, size_t ws_size,
                              hipStream_t stream) {
  (void)in_sizes; (void)n_in; (void)out_size; (void)ws_size;
  // dict order: [0]emb1_0 [1]emb2_0 [2]cert1_0 [3]cert2_0 [4]alpha_0 [5]beta_0
  //             [6..11] layer1, [12..17] layer2, [18]link_0 [19]link_1
  float* ws = (float*)d_ws;
  PackArgs pa;
  pa.src[0] = (const float*)d_in[0];  pa.src[1] = (const float*)d_in[6];  pa.src[2] = (const float*)d_in[12];
  pa.src[3] = (const float*)d_in[1];  pa.src[4] = (const float*)d_in[7];  pa.src[5] = (const float*)d_in[13];
  pa.src[6] = (const float*)d_in[8];  pa.src[7] = (const float*)d_in[14];
  pa.src[8] = (const float*)d_in[9];  pa.src[9] = (const float*)d_in[15];
  hipLaunchKernelGGL(prep_kernel, dim3(1344), dim3(256), 0, stream, pa,
                     (const float*)d_in[18], (const float*)d_in[19],
                     (const float*)d_in[10], (const float*)d_in[11],
                     (const float*)d_in[16], (const float*)d_in[17], ws);
  hipLaunchKernelGGL(prep2_kernel, dim3(256), dim3(256), 0, stream, ws);
  hipLaunchKernelGGL(main_kernel, dim3(2048), dim3(256), 0, stream,
                     (const float*)ws, (float*)d_out);
}